// Round 1
// baseline (142.482 us; speedup 1.0000x reference)
//
#include <hip/hip_runtime.h>
#include <hip/hip_bf16.h>

// Mean-shift: 3 iterations of X <- eta * X @ (K/deg) + (1-eta) * X,
// K = exp(2 * X^T X), D=32, N=9216. Fused attention formulation.
// R5: R4 (137us) was LDS-BW + VALU bound, MFMA pipe ~90% idle (~1.5KB LDS
// traffic per MFMA; 875 LDS-cyc vs 155 MFMA-cyc per CU-chunk). This round:
//  - 32 queries/wave (two A-frags): every shared B-frag read feeds 2 MFMAs
//    -> LDS bytes/MFMA 1.5KB -> 1.0KB.
//  - den accumulated on the idle MFMA pipe (ones B-frag) instead of 32
//    v_add_f32/lane-chunk + epilogue shuffle; num/den now use identical
//    bf16-rounded P (exactly consistent normalization).
//  - staging via global_load_lds width=16 (layout is linear per wave:
//    lane i at base + i*16B) -> no register round-trip.
//  - 4-wave blocks, KSEG=14, grid 72x14=1008 ~= 4 blocks/CU: same 16
//    waves/CU, but 4 independent blocks decouple the per-chunk barriers.
//    Partials double to 16.5MB/iter but sit in the 256MB L3.

#define DIM 32
#define RESO 96
#define NPT (RESO * RESO)          // 9216
#define NITER 3
#define ETA 0.5f
#define SCALE 2.88539008f          // BW * log2(e) = 2 * 1.4426950408

#define QB 128                     // queries per block (4 waves x 32)
#define NQB (NPT / QB)             // 72
#define KSEG 14                    // key segments (grid.y)
#define NCHUNK_TOT (NPT / 64)      // 144 chunks of 64 keys
#define PSTRIDE 72                 // P-slab row stride in elems (144 B)

typedef __bf16 bf16_t;
typedef __bf16 v8bf __attribute__((ext_vector_type(8)));
typedef float  v4f  __attribute__((ext_vector_type(4)));

// Async global->LDS, 16B per lane. LDS dest is wave-uniform base + lane*16B
// (our tile layout is exactly that); global src is per-lane.
__device__ __forceinline__ void gload_lds16(const bf16_t* g, bf16_t* l) {
    __builtin_amdgcn_global_load_lds(
        (const __attribute__((address_space(1))) void*)g,
        (__attribute__((address_space(3))) void*)l, 16, 0, 0);
}

// One-time pack of fp32 X (DIM x NPT) into bf16 row-major (NPT x DIM) and
// bf16 col-major (DIM x NPT); also copies X into d_out slice 0.
__global__ void pack_kernel(const float* __restrict__ X,
                            bf16_t* __restrict__ rows,
                            bf16_t* __restrict__ cols,
                            float* __restrict__ out_copy) {
    int idx = blockIdx.x * 256 + threadIdx.x;
    if (idx >= DIM * NPT) return;
    int d = idx / NPT;
    int n = idx - d * NPT;
    float v = X[idx];
    cols[idx] = (bf16_t)v;
    rows[n * DIM + d] = (bf16_t)v;
    out_copy[idx] = v;
}

// Fused mean-shift partial kernel. Block = 256 thr = 4 waves; wave w owns
// queries [qb*128 + w*32, +32) (two 16-row MFMA tiles). All waves consume the
// same 64-key chunk from shared LDS tiles (double-buffered, global_load_lds
// staged, one barrier per chunk). Block covers key segment ks; writes fp32
// num/den partials.
__global__ __launch_bounds__(256, 4)
void msattn_kernel(const float* __restrict__ Xcur,
                   const bf16_t* __restrict__ rows,
                   const bf16_t* __restrict__ cols,
                   float* __restrict__ part_num,
                   float* __restrict__ part_den) {
    // tiles[buf]: [0..2047] = tileA (GEMM1 B, read-order; subtile t at t*512
    // elems, lane offset lane*8): element = key kc+4*l16+t, dims quad*8..
    // [2048..4095] = tileB (GEMM2 B; frag r=(h<<1|g) at 2048+r*512): element =
    // V^T[dim h*16+l16][keys kc+g*32+quad*8..]. Lane i reads base+i*16B.
    __shared__ __align__(16) bf16_t tiles[2][4096];
    __shared__ __align__(16) bf16_t pslab[4][32 * PSTRIDE];

    const int tid  = threadIdx.x;
    const int w    = tid >> 6;
    const int lane = tid & 63;
    const int quad = lane >> 4;
    const int l16  = lane & 15;
    const int qb   = blockIdx.x;
    const int ks   = blockIdx.y;
    const int c0   = (NCHUNK_TOT * ks) / KSEG;
    const int c1   = (NCHUNK_TOT * (ks + 1)) / KSEG;
    const int q0w  = qb * QB + w * 32;

    bf16_t* p_lds = pslab[w];

    // A-frags: A[m=l16 (query)][k=quad*8+j (dim)], BW*log2e folded in.
    v8bf afrag0, afrag1;
#pragma unroll
    for (int j = 0; j < 8; ++j) {
        float v0 = Xcur[(quad * 8 + j) * NPT + q0w + l16];
        float v1 = Xcur[(quad * 8 + j) * NPT + q0w + 16 + l16];
        afrag0[j] = (bf16_t)(v0 * SCALE);
        afrag1[j] = (bf16_t)(v1 * SCALE);
    }

    v8bf ones;
#pragma unroll
    for (int j = 0; j < 8; ++j) ones[j] = (bf16_t)1.0f;

    // Staging sources: wave w stages tileA subtile t=w AND tileB frag r=w
    // (1KB each per chunk via one global_load_lds dwordx4 apiece).
    const bf16_t* gA = rows + ((size_t)c0 * 64 + 4 * l16 + w) * DIM + quad * 8;
    const int hh = w >> 1, gg = w & 1;
    const bf16_t* gB = cols + (size_t)(hh * 16 + l16) * NPT + c0 * 64 + gg * 32 + quad * 8;

    v4f acc00 = {0.f, 0.f, 0.f, 0.f};   // qgroup0, dims 0..15
    v4f acc01 = {0.f, 0.f, 0.f, 0.f};   // qgroup0, dims 16..31
    v4f acc10 = {0.f, 0.f, 0.f, 0.f};   // qgroup1, dims 0..15
    v4f acc11 = {0.f, 0.f, 0.f, 0.f};   // qgroup1, dims 16..31
    v4f dden0 = {0.f, 0.f, 0.f, 0.f};   // qgroup0 den (all cols equal)
    v4f dden1 = {0.f, 0.f, 0.f, 0.f};   // qgroup1 den

    // Prologue: stage first chunk into buffer 0 (barrier drains vmcnt).
    gload_lds16(gA, &tiles[0][w * 512]);
    gload_lds16(gB, &tiles[0][2048 + w * 512]);
    gA += 64 * DIM;
    gB += 64;
    __syncthreads();

    for (int c = c0; c < c1; ++c) {
        const int cc = c - c0;
        const bf16_t* tb = tiles[cc & 1];

        // Issue next chunk's staging loads first; they stay in flight across
        // this chunk's compute and are drained by the end-of-chunk barrier.
        if (c + 1 < c1) {
            bf16_t* nt = tiles[(cc + 1) & 1];
            gload_lds16(gA, &nt[w * 512]);
            gload_lds16(gB, &nt[2048 + w * 512]);
            gA += 64 * DIM;
            gB += 64;
        }

        // --- GEMM1: S subtile t, column n=l16 <-> key kc+4*n+t; each shared
        // B-frag read feeds both query groups. ---
        v4f s0[4], s1[4];
#pragma unroll
        for (int t = 0; t < 4; ++t) {
            v8bf b = *(const v8bf*)&tb[t * 512 + lane * 8];
            s0[t] = __builtin_amdgcn_mfma_f32_16x16x32_bf16(afrag0, b,
                        (v4f){0.f, 0.f, 0.f, 0.f}, 0, 0, 0);
            s1[t] = __builtin_amdgcn_mfma_f32_16x16x32_bf16(afrag1, b,
                        (v4f){0.f, 0.f, 0.f, 0.f}, 0, 0, 0);
        }

        // --- exp2 + pack 4 bf16 -> one b64 store per (qgroup, r) ---
        // C-layout: (q=quad*4+r, col l16) = S[q][key kc+4*l16+t]; store at
        // P position 4*l16+t (position p <-> key kc+p: identity).
#pragma unroll
        for (int r = 0; r < 4; ++r) {
            union { bf16_t hv[4]; unsigned long long u; } pk0, pk1;
#pragma unroll
            for (int t = 0; t < 4; ++t) {
                pk0.hv[t] = (bf16_t)__builtin_amdgcn_exp2f(s0[t][r]);
                pk1.hv[t] = (bf16_t)__builtin_amdgcn_exp2f(s1[t][r]);
            }
            *(unsigned long long*)&p_lds[(quad * 4 + r) * PSTRIDE + 4 * l16] = pk0.u;
            *(unsigned long long*)&p_lds[(16 + quad * 4 + r) * PSTRIDE + 4 * l16] = pk1.u;
        }

        // --- GEMM2: O[q][d] += P[q][k] V[k][d]; den rides the MFMA pipe via
        // an all-ones B-frag (wave-local LDS, in-order reads). ---
        v8bf b00 = *(const v8bf*)&tb[2048 + 0 * 512 + lane * 8];  // h0,g0
        v8bf b01 = *(const v8bf*)&tb[2048 + 1 * 512 + lane * 8];  // h0,g1
        v8bf b10 = *(const v8bf*)&tb[2048 + 2 * 512 + lane * 8];  // h1,g0
        v8bf b11 = *(const v8bf*)&tb[2048 + 3 * 512 + lane * 8];  // h1,g1

        v8bf a0 = *(const v8bf*)&p_lds[l16 * PSTRIDE + quad * 8];        // qg0 pos 0..31
        v8bf a1 = *(const v8bf*)&p_lds[l16 * PSTRIDE + 32 + quad * 8];   // qg0 pos 32..63
        acc00 = __builtin_amdgcn_mfma_f32_16x16x32_bf16(a0, b00, acc00, 0, 0, 0);
        acc01 = __builtin_amdgcn_mfma_f32_16x16x32_bf16(a0, b10, acc01, 0, 0, 0);
        dden0 = __builtin_amdgcn_mfma_f32_16x16x32_bf16(a0, ones, dden0, 0, 0, 0);
        acc00 = __builtin_amdgcn_mfma_f32_16x16x32_bf16(a1, b01, acc00, 0, 0, 0);
        acc01 = __builtin_amdgcn_mfma_f32_16x16x32_bf16(a1, b11, acc01, 0, 0, 0);
        dden0 = __builtin_amdgcn_mfma_f32_16x16x32_bf16(a1, ones, dden0, 0, 0, 0);

        v8bf a2 = *(const v8bf*)&p_lds[(16 + l16) * PSTRIDE + quad * 8];       // qg1 pos 0..31
        v8bf a3 = *(const v8bf*)&p_lds[(16 + l16) * PSTRIDE + 32 + quad * 8];  // qg1 pos 32..63
        acc10 = __builtin_amdgcn_mfma_f32_16x16x32_bf16(a2, b00, acc10, 0, 0, 0);
        acc11 = __builtin_amdgcn_mfma_f32_16x16x32_bf16(a2, b10, acc11, 0, 0, 0);
        dden1 = __builtin_amdgcn_mfma_f32_16x16x32_bf16(a2, ones, dden1, 0, 0, 0);
        acc10 = __builtin_amdgcn_mfma_f32_16x16x32_bf16(a3, b01, acc10, 0, 0, 0);
        acc11 = __builtin_amdgcn_mfma_f32_16x16x32_bf16(a3, b11, acc11, 0, 0, 0);
        dden1 = __builtin_amdgcn_mfma_f32_16x16x32_bf16(a3, ones, dden1, 0, 0, 0);

        __syncthreads();
    }

    // --- epilogue: each wave owns its 32 queries outright; den comes straight
    // out of the MFMA accumulator (all 16 cols equal -> read col l16==0). ---
    float* pn = part_num + (size_t)ks * NPT * DIM;
#pragma unroll
    for (int r = 0; r < 4; ++r) {
        int gq0 = q0w + quad * 4 + r;
        int gq1 = gq0 + 16;
        pn[(size_t)gq0 * DIM + l16]      = acc00[r];
        pn[(size_t)gq0 * DIM + 16 + l16] = acc01[r];
        pn[(size_t)gq1 * DIM + l16]      = acc10[r];
        pn[(size_t)gq1 * DIM + 16 + l16] = acc11[r];
    }
    if (l16 == 0) {
#pragma unroll
        for (int r = 0; r < 4; ++r) {
            part_den[ks * NPT + q0w + quad * 4 + r]      = dden0[r];
            part_den[ks * NPT + q0w + 16 + quad * 4 + r] = dden1[r];
        }
    }
}

// Reduce KSEG partials, apply eta-step, write Xnext + next iteration's bf16
// rows/cols. Tiled 32q x 32d with LDS transpose so every global access is
// coalesced. Grid = NPT/32 = 288 blocks x 256 threads.
__global__ __launch_bounds__(256, 4)
void reduce_kernel(const float* __restrict__ part_num,
                   const float* __restrict__ part_den,
                   const float* __restrict__ Xcur,
                   float* __restrict__ Xnext,
                   bf16_t* __restrict__ rows_out,
                   bf16_t* __restrict__ cols_out) {
    __shared__ float tnum[32][33];
    __shared__ float txn[32][33];
    __shared__ float tden[32];

    const int tid = threadIdx.x;
    const int q0  = blockIdx.x * 32;

    // pass 1 (q-major, coalesced partial reads)
#pragma unroll
    for (int j = 0; j < 4; ++j) {
        int idx = tid + j * 256;
        int qq = idx >> 5, d = idx & 31;
        float s = 0.f;
#pragma unroll
        for (int ss = 0; ss < KSEG; ++ss)
            s += part_num[((size_t)ss * NPT + q0 + qq) * DIM + d];
        tnum[qq][d] = s;
    }
    if (tid < 32) {
        float s = 0.f;
#pragma unroll
        for (int ss = 0; ss < KSEG; ++ss)
            s += part_den[ss * NPT + q0 + tid];
        tden[tid] = s;
    }
    __syncthreads();

    // pass 2 (d-major: Xcur read, Xnext + cols_out writes coalesced)
#pragma unroll
    for (int j = 0; j < 4; ++j) {
        int idx = tid + j * 256;
        int d = idx >> 5, qq = idx & 31;
        float num = tnum[qq][d];
        float dn  = tden[qq];
        float xo  = Xcur[d * NPT + q0 + qq];
        float xn  = ETA * num / dn + (1.0f - ETA) * xo;
        Xnext[d * NPT + q0 + qq] = xn;
        cols_out[(size_t)d * NPT + q0 + qq] = (bf16_t)xn;
        txn[qq][d] = xn;
    }
    __syncthreads();

    // pass 3 (q-major: rows_out coalesced)
#pragma unroll
    for (int j = 0; j < 4; ++j) {
        int idx = tid + j * 256;
        int qq = idx >> 5, d = idx & 31;
        rows_out[(size_t)(q0 + qq) * DIM + d] = (bf16_t)txn[qq][d];
    }
}

extern "C" void kernel_launch(void* const* d_in, const int* in_sizes, int n_in,
                              void* d_out, int out_size, void* d_ws, size_t ws_size,
                              hipStream_t stream) {
    const float* x_in = (const float*)d_in[0];
    float* out = (float*)d_out;

    const size_t DN = (size_t)DIM * NPT;
    // Workspace: 4 bf16 pack buffers (ping-pong), fp32 partials.
    bf16_t* rows0 = (bf16_t*)d_ws;
    bf16_t* cols0 = rows0 + DN;
    bf16_t* rows1 = cols0 + DN;
    bf16_t* cols1 = rows1 + DN;
    float* part_num = (float*)(cols1 + DN);                 // KSEG * NPT * DIM f32
    float* part_den = part_num + (size_t)KSEG * NPT * DIM;  // KSEG * NPT f32

    const int pack_blocks = (DIM * NPT + 255) / 256;   // 1152
    pack_kernel<<<pack_blocks, 256, 0, stream>>>(x_in, rows0, cols0, out);

    for (int it = 0; it < NITER; ++it) {
        const float* Xcur = (it == 0) ? x_in : out + (size_t)it * DN;
        bf16_t* rin  = (it & 1) ? rows1 : rows0;
        bf16_t* cin  = (it & 1) ? cols1 : cols0;
        bf16_t* rout = (it & 1) ? rows0 : rows1;
        bf16_t* cout = (it & 1) ? cols0 : cols1;
        msattn_kernel<<<dim3(NQB, KSEG), 256, 0, stream>>>(Xcur, rin, cin,
                                                           part_num, part_den);
        reduce_kernel<<<NPT / 32, 256, 0, stream>>>(part_num, part_den, Xcur,
                                                    out + (size_t)(it + 1) * DN,
                                                    rout, cout);
    }
}

// Round 2
// 139.774 us; speedup vs baseline: 1.0194x; 1.0194x over previous
//
#include <hip/hip_runtime.h>
#include <hip/hip_bf16.h>

// Mean-shift: 3 iterations of X <- eta * X @ (K/deg) + (1-eta) * X,
// K = exp(2 * X^T X), D=32, N=9216. Fused attention formulation.
// R6: R5 (KSEG=14, 4-wave, 32q/wave) regressed 136->142: the doubled
// partial-reduce tax (+16.5MB/iter written+re-read, reduce latency-bound)
// ate the msattn LDS savings -- and the LDS cut itself bought ~nothing,
// falsifying the LDS-BW theory (pipe sums say ~18us/iter vs ~40 observed:
// latency/phase-stall bound). R6 reverts to the proven R4 geometry
// (8-wave/512thr, 16q/wave, KSEG=7, 2 blocks/CU) and keeps only the
// geometry-neutral wins:
//  - global_load_lds width=16 staging (no reg round-trip, no ds_write).
//  - den on the MFMA pipe via all-ones B-frag (kills 16 VALU adds/lane/chunk
//    + epilogue shuffle-reduce; num/den use identical bf16-rounded P).
//  - s_setprio(1) around MFMA clusters (2 independent blocks/CU at
//    decorrelated phases = role-diversity regime, T5).
//  - float4-vectorized reduce pass-1 (latency-bound at 1.1 blocks/CU).

#define DIM 32
#define RESO 96
#define NPT (RESO * RESO)          // 9216
#define NITER 3
#define ETA 0.5f
#define SCALE 2.88539008f          // BW * log2(e) = 2 * 1.4426950408

#define QB 128                     // queries per block (8 waves x 16)
#define NQB (NPT / QB)             // 72
#define KSEG 7                     // key segments (grid.y)
#define NCHUNK_TOT (NPT / 64)      // 144 chunks of 64 keys
#define PSTRIDE 72                 // P-slab row stride in elems (144 B)

typedef __bf16 bf16_t;
typedef __bf16 v8bf __attribute__((ext_vector_type(8)));
typedef float  v4f  __attribute__((ext_vector_type(4)));

// Async global->LDS, 16B per lane. LDS dest is wave-uniform base + lane*16B
// (our tile layout is exactly that); global src is per-lane.
__device__ __forceinline__ void gload_lds16(const bf16_t* g, bf16_t* l) {
    __builtin_amdgcn_global_load_lds(
        (const __attribute__((address_space(1))) void*)g,
        (__attribute__((address_space(3))) void*)l, 16, 0, 0);
}

// One-time pack of fp32 X (DIM x NPT) into bf16 row-major (NPT x DIM) and
// bf16 col-major (DIM x NPT); also copies X into d_out slice 0.
__global__ void pack_kernel(const float* __restrict__ X,
                            bf16_t* __restrict__ rows,
                            bf16_t* __restrict__ cols,
                            float* __restrict__ out_copy) {
    int idx = blockIdx.x * 256 + threadIdx.x;
    if (idx >= DIM * NPT) return;
    int d = idx / NPT;
    int n = idx - d * NPT;
    float v = X[idx];
    cols[idx] = (bf16_t)v;
    rows[n * DIM + d] = (bf16_t)v;
    out_copy[idx] = v;
}

// Fused mean-shift partial kernel. Block = 512 thr = 8 waves; wave w owns
// queries [qb*128 + w*16, +16). All waves consume the same 64-key chunk from
// shared LDS tiles (double-buffered, global_load_lds staged, one barrier per
// chunk). Block covers key segment ks; writes fp32 num/den partials.
__global__ __launch_bounds__(512, 4)
void msattn_kernel(const float* __restrict__ Xcur,
                   const bf16_t* __restrict__ rows,
                   const bf16_t* __restrict__ cols,
                   float* __restrict__ part_num,
                   float* __restrict__ part_den) {
    // tiles[buf]: [0..2047] = tileA (GEMM1 B, read-order; subtile t at t*512
    // elems, lane offset lane*8): element = key kc+4*l16+t, dims quad*8..
    // [2048..4095] = tileB (GEMM2 B; frag r=(h<<1|g) at 2048+r*512): element =
    // V^T[dim h*16+l16][keys kc+g*32+quad*8..]. Lane i reads base+i*16B:
    // conflict-free by construction; global_load_lds writes linearly.
    __shared__ __align__(16) bf16_t tiles[2][4096];
    __shared__ __align__(16) bf16_t pslab[8][16 * PSTRIDE];

    const int tid  = threadIdx.x;
    const int w    = tid >> 6;
    const int lane = tid & 63;
    const int quad = lane >> 4;
    const int l16  = lane & 15;
    const int qb   = blockIdx.x;
    const int ks   = blockIdx.y;
    const int c0   = (NCHUNK_TOT * ks) / KSEG;
    const int c1   = (NCHUNK_TOT * (ks + 1)) / KSEG;
    const int q0w  = qb * QB + w * 16;

    bf16_t* p_lds = pslab[w];

    // A-frag: A[m=l16 (query)][k=quad*8+j (dim)], BW*log2e folded in.
    v8bf afrag;
#pragma unroll
    for (int j = 0; j < 8; ++j) {
        float v = Xcur[(quad * 8 + j) * NPT + q0w + l16];
        afrag[j] = (bf16_t)(v * SCALE);
    }

    v8bf ones;
#pragma unroll
    for (int j = 0; j < 8; ++j) ones[j] = (bf16_t)1.0f;

    // Per-wave staging source (each wave stages one 1KB piece per chunk via
    // one global_load_lds dwordx4; dest = tiles[buf][w*512 + lane*8]).
    const bf16_t* gsrc;
    int gdelta;
    if (w < 4) {           // tileA subtile t=w: key kc+4*l16+w, dims quad*8..
        gsrc = rows + ((size_t)c0 * 64 + 4 * l16 + w) * DIM + quad * 8;
        gdelta = 64 * DIM;
    } else {               // tileB frag r=w-4=(h<<1|g): dim h*16+l16, keys kc+g*32+quad*8..
        int r = w - 4, h = r >> 1, g = r & 1;
        gsrc = cols + (size_t)(h * 16 + l16) * NPT + c0 * 64 + g * 32 + quad * 8;
        gdelta = 64;
    }

    v4f acc0 = {0.f, 0.f, 0.f, 0.f};   // O partial, dims 0..15
    v4f acc1 = {0.f, 0.f, 0.f, 0.f};   // O partial, dims 16..31
    v4f dden = {0.f, 0.f, 0.f, 0.f};   // den (all 16 cols equal)

    // Prologue: stage first chunk into buffer 0 (barrier drains vmcnt).
    gload_lds16(gsrc, &tiles[0][w * 512]);
    gsrc += gdelta;
    __syncthreads();

    for (int c = c0; c < c1; ++c) {
        const int cc = c - c0;
        const bf16_t* tb = tiles[cc & 1];

        // Issue next chunk's staging load first; it stays in flight across
        // this chunk's compute and is drained by the end-of-chunk barrier.
        if (c + 1 < c1) {
            gload_lds16(gsrc, &tiles[(cc + 1) & 1][w * 512]);
            gsrc += gdelta;
        }

        // --- GEMM1: S subtile t, column n=l16 <-> key kc+4*n+t ---
        v4f s[4];
        __builtin_amdgcn_s_setprio(1);
#pragma unroll
        for (int t = 0; t < 4; ++t) {
            v8bf b = *(const v8bf*)&tb[t * 512 + lane * 8];
            s[t] = __builtin_amdgcn_mfma_f32_16x16x32_bf16(afrag, b,
                        (v4f){0.f, 0.f, 0.f, 0.f}, 0, 0, 0);
        }
        __builtin_amdgcn_s_setprio(0);

        // --- exp2 + pack 4 bf16 -> one b64 store per r ---
        // C-layout: (q=quad*4+r, col l16) = S[q][key kc+4*l16+t]; store at
        // P position 4*l16+t (position p <-> key kc+p: identity).
#pragma unroll
        for (int r = 0; r < 4; ++r) {
            union { bf16_t hv[4]; unsigned long long u; } pk;
#pragma unroll
            for (int t = 0; t < 4; ++t)
                pk.hv[t] = (bf16_t)__builtin_amdgcn_exp2f(s[t][r]);
            *(unsigned long long*)&p_lds[(quad * 4 + r) * PSTRIDE + 4 * l16] = pk.u;
        }

        // --- GEMM2: O[q][d] += P[q][k] V[k][d]; den rides the MFMA pipe via
        // an all-ones B-frag (wave-local LDS, in-order reads). ---
        v8bf a20 = *(const v8bf*)&p_lds[l16 * PSTRIDE + quad * 8];        // positions 0..31
        v8bf a21 = *(const v8bf*)&p_lds[l16 * PSTRIDE + 32 + quad * 8];   // positions 32..63
        v8bf b00 = *(const v8bf*)&tb[2048 + 0 * 512 + lane * 8];  // h0,g0
        v8bf b01 = *(const v8bf*)&tb[2048 + 1 * 512 + lane * 8];  // h0,g1
        v8bf b10 = *(const v8bf*)&tb[2048 + 2 * 512 + lane * 8];  // h1,g0
        v8bf b11 = *(const v8bf*)&tb[2048 + 3 * 512 + lane * 8];  // h1,g1
        __builtin_amdgcn_s_setprio(1);
        acc0 = __builtin_amdgcn_mfma_f32_16x16x32_bf16(a20, b00, acc0, 0, 0, 0);
        acc1 = __builtin_amdgcn_mfma_f32_16x16x32_bf16(a20, b10, acc1, 0, 0, 0);
        dden = __builtin_amdgcn_mfma_f32_16x16x32_bf16(a20, ones, dden, 0, 0, 0);
        acc0 = __builtin_amdgcn_mfma_f32_16x16x32_bf16(a21, b01, acc0, 0, 0, 0);
        acc1 = __builtin_amdgcn_mfma_f32_16x16x32_bf16(a21, b11, acc1, 0, 0, 0);
        dden = __builtin_amdgcn_mfma_f32_16x16x32_bf16(a21, ones, dden, 0, 0, 0);
        __builtin_amdgcn_s_setprio(0);

        __syncthreads();
    }

    // --- epilogue: each wave owns its 16 queries outright; den comes straight
    // out of the MFMA accumulator (all 16 cols equal -> lane l16==0's copy). ---
    float* pn = part_num + (size_t)ks * NPT * DIM;
#pragma unroll
    for (int r = 0; r < 4; ++r) {
        int gq = q0w + quad * 4 + r;
        pn[(size_t)gq * DIM + l16]      = acc0[r];
        pn[(size_t)gq * DIM + 16 + l16] = acc1[r];
    }
    if (l16 == 0) {
#pragma unroll
        for (int r = 0; r < 4; ++r)
            part_den[ks * NPT + q0w + quad * 4 + r] = dden[r];
    }
}

// Reduce KSEG partials, apply eta-step, write Xnext + next iteration's bf16
// rows/cols. Tiled 32q x 32d with LDS transpose so every global access is
// coalesced; pass 1 reads partials as float4 (latency-bound at ~1.1
// blocks/CU -> MLP matters). Grid = NPT/32 = 288 blocks x 256 threads.
__global__ __launch_bounds__(256, 4)
void reduce_kernel(const float* __restrict__ part_num,
                   const float* __restrict__ part_den,
                   const float* __restrict__ Xcur,
                   float* __restrict__ Xnext,
                   bf16_t* __restrict__ rows_out,
                   bf16_t* __restrict__ cols_out) {
    __shared__ float tnum[32][33];
    __shared__ float txn[32][33];
    __shared__ float tden[32];

    const int tid = threadIdx.x;
    const int q0  = blockIdx.x * 32;

    // pass 1 (q-major, coalesced float4 partial reads: 256 thr = 32q x 8dq)
    {
        int qq = tid >> 3, dq = tid & 7;
        v4f s = {0.f, 0.f, 0.f, 0.f};
#pragma unroll
        for (int ss = 0; ss < KSEG; ++ss)
            s += *(const v4f*)&part_num[((size_t)ss * NPT + q0 + qq) * DIM + dq * 4];
#pragma unroll
        for (int k = 0; k < 4; ++k) tnum[qq][dq * 4 + k] = s[k];
    }
    if (tid < 32) {
        float s = 0.f;
#pragma unroll
        for (int ss = 0; ss < KSEG; ++ss)
            s += part_den[ss * NPT + q0 + tid];
        tden[tid] = s;
    }
    __syncthreads();

    // pass 2 (d-major: Xcur read, Xnext + cols_out writes coalesced)
#pragma unroll
    for (int j = 0; j < 4; ++j) {
        int idx = tid + j * 256;
        int d = idx >> 5, qq = idx & 31;
        float num = tnum[qq][d];
        float dn  = tden[qq];
        float xo  = Xcur[d * NPT + q0 + qq];
        float xn  = ETA * num / dn + (1.0f - ETA) * xo;
        Xnext[d * NPT + q0 + qq] = xn;
        cols_out[(size_t)d * NPT + q0 + qq] = (bf16_t)xn;
        txn[qq][d] = xn;
    }
    __syncthreads();

    // pass 3 (q-major: rows_out coalesced)
#pragma unroll
    for (int j = 0; j < 4; ++j) {
        int idx = tid + j * 256;
        int qq = idx >> 5, d = idx & 31;
        rows_out[(size_t)(q0 + qq) * DIM + d] = (bf16_t)txn[qq][d];
    }
}

extern "C" void kernel_launch(void* const* d_in, const int* in_sizes, int n_in,
                              void* d_out, int out_size, void* d_ws, size_t ws_size,
                              hipStream_t stream) {
    const float* x_in = (const float*)d_in[0];
    float* out = (float*)d_out;

    const size_t DN = (size_t)DIM * NPT;
    // Workspace: 4 bf16 pack buffers (ping-pong), fp32 partials.
    bf16_t* rows0 = (bf16_t*)d_ws;
    bf16_t* cols0 = rows0 + DN;
    bf16_t* rows1 = cols0 + DN;
    bf16_t* cols1 = rows1 + DN;
    float* part_num = (float*)(cols1 + DN);                 // KSEG * NPT * DIM f32
    float* part_den = part_num + (size_t)KSEG * NPT * DIM;  // KSEG * NPT f32

    const int pack_blocks = (DIM * NPT + 255) / 256;   // 1152
    pack_kernel<<<pack_blocks, 256, 0, stream>>>(x_in, rows0, cols0, out);

    for (int it = 0; it < NITER; ++it) {
        const float* Xcur = (it == 0) ? x_in : out + (size_t)it * DN;
        bf16_t* rin  = (it & 1) ? rows1 : rows0;
        bf16_t* cin  = (it & 1) ? cols1 : cols0;
        bf16_t* rout = (it & 1) ? rows0 : rows1;
        bf16_t* cout = (it & 1) ? cols0 : cols1;
        msattn_kernel<<<dim3(NQB, KSEG), 512, 0, stream>>>(Xcur, rin, cin,
                                                           part_num, part_den);
        reduce_kernel<<<NPT / 32, 256, 0, stream>>>(part_num, part_den, Xcur,
                                                    out + (size_t)(it + 1) * DN,
                                                    rout, cout);
    }
}

// Round 3
// 137.809 us; speedup vs baseline: 1.0339x; 1.0143x over previous
//
#include <hip/hip_runtime.h>
#include <hip/hip_bf16.h>

// Mean-shift: 3 iterations of X <- eta * X @ (K/deg) + (1-eta) * X,
// K = exp(2 * X^T X), D=32, N=9216. Fused attention formulation.
// R7: R4-R6 showed total time is insensitive to per-chunk pipe work
// (LDS -36%, VALU den->MFMA den, staging style: all <5% effect) while
// pipe sums say ~8us/iter vs ~40 observed -> time = per-chunk fixed
// overhead (full-drain barrier convoy + serial GEMM1->exp2->GEMM2 chain,
// only 4 waves/SIMD) x chunk count. R7 halves the chunk count: 128-key
// chunks = two 64-key halves per barrier. 72 chunks128 split into 7
// whole-chunk segments (10,10,10,11,10,10,11) -- no tail. P-slab reused
// across halves (WAR ordered by lgkmcnt) -> LDS 51.2KB, 2 blocks/CU.
// setprio dropped (m190: hurts lockstep GEMM; was part of R6 regression).
// Kept: global_load_lds width=16 staging, den on MFMA pipe, vectorized
// reduce pass-1.

#define DIM 32
#define RESO 96
#define NPT (RESO * RESO)          // 9216
#define NITER 3
#define ETA 0.5f
#define SCALE 2.88539008f          // BW * log2(e) = 2 * 1.4426950408

#define QB 128                     // queries per block (8 waves x 16)
#define NQB (NPT / QB)             // 72
#define KSEG 7                     // key segments (grid.y)
#define NCHUNK128 (NPT / 128)      // 72 chunks of 128 keys
#define PSTRIDE 72                 // P-slab row stride in elems (144 B)

typedef __bf16 bf16_t;
typedef __bf16 v8bf __attribute__((ext_vector_type(8)));
typedef float  v4f  __attribute__((ext_vector_type(4)));

// Async global->LDS, 16B per lane. LDS dest is wave-uniform base + lane*16B
// (our tile layout is exactly that); global src is per-lane.
__device__ __forceinline__ void gload_lds16(const bf16_t* g, bf16_t* l) {
    __builtin_amdgcn_global_load_lds(
        (const __attribute__((address_space(1))) void*)g,
        (__attribute__((address_space(3))) void*)l, 16, 0, 0);
}

// One-time pack of fp32 X (DIM x NPT) into bf16 row-major (NPT x DIM) and
// bf16 col-major (DIM x NPT); also copies X into d_out slice 0.
__global__ void pack_kernel(const float* __restrict__ X,
                            bf16_t* __restrict__ rows,
                            bf16_t* __restrict__ cols,
                            float* __restrict__ out_copy) {
    int idx = blockIdx.x * 256 + threadIdx.x;
    if (idx >= DIM * NPT) return;
    int d = idx / NPT;
    int n = idx - d * NPT;
    float v = X[idx];
    cols[idx] = (bf16_t)v;
    rows[n * DIM + d] = (bf16_t)v;
    out_copy[idx] = v;
}

// Fused mean-shift partial kernel. Block = 512 thr = 8 waves; wave w owns
// queries [qb*128 + w*16, +16). All waves consume the same 128-key chunk
// (two 64-key halves) from shared LDS tiles (double-buffered,
// global_load_lds staged, ONE barrier per 128-key chunk). Block covers key
// segment ks; writes fp32 num/den partials.
__global__ __launch_bounds__(512, 4)
void msattn_kernel(const float* __restrict__ Xcur,
                   const bf16_t* __restrict__ rows,
                   const bf16_t* __restrict__ cols,
                   float* __restrict__ part_num,
                   float* __restrict__ part_den) {
    // tiles[buf]: two 4096-elem halves (h=0/1, 64 keys each). Within half h:
    // [0..2047] = tileA (GEMM1 B, read-order; subtile t at t*512 elems, lane
    // offset lane*8): element = key kc+h*64+4*l16+t, dims quad*8..
    // [2048..4095] = tileB (GEMM2 B; frag r=(hh<<1|g) at 2048+r*512): element
    // = V^T[dim hh*16+l16][keys kc+h*64+g*32+quad*8..]. Lane i reads
    // base+i*16B: conflict-free; global_load_lds writes linearly.
    __shared__ __align__(16) bf16_t tiles[2][8192];
    __shared__ __align__(16) bf16_t pslab[8][16 * PSTRIDE];

    const int tid  = threadIdx.x;
    const int w    = tid >> 6;
    const int lane = tid & 63;
    const int quad = lane >> 4;
    const int l16  = lane & 15;
    const int qb   = blockIdx.x;
    const int ks   = blockIdx.y;
    const int c0   = (NCHUNK128 * ks) / KSEG;
    const int c1   = (NCHUNK128 * (ks + 1)) / KSEG;
    const int q0w  = qb * QB + w * 16;

    bf16_t* p_lds = pslab[w];

    // A-frag: A[m=l16 (query)][k=quad*8+j (dim)], BW*log2e folded in.
    v8bf afrag;
#pragma unroll
    for (int j = 0; j < 8; ++j) {
        float v = Xcur[(quad * 8 + j) * NPT + q0w + l16];
        afrag[j] = (bf16_t)(v * SCALE);
    }

    v8bf ones;
#pragma unroll
    for (int j = 0; j < 8; ++j) ones[j] = (bf16_t)1.0f;

    // Per-wave staging source: wave w stages one 1KB piece per 64-key half
    // (2 gload_lds dwordx4 per 128-key chunk). dest = buf[h*4096 + roleoff +
    // lane*8].
    const bf16_t* gsrc;
    int gdelta, hdelta, dstoff;
    if (w < 4) {           // tileA subtile t=w: key kc+4*l16+w, dims quad*8..
        gsrc = rows + ((size_t)c0 * 128 + 4 * l16 + w) * DIM + quad * 8;
        gdelta = 128 * DIM;
        hdelta = 64 * DIM;
        dstoff = w * 512;
    } else {               // tileB frag r=w-4=(hh<<1|g): dim hh*16+l16, keys kc+g*32+quad*8..
        int r = w - 4, hh = r >> 1, g = r & 1;
        gsrc = cols + (size_t)(hh * 16 + l16) * NPT + c0 * 128 + g * 32 + quad * 8;
        gdelta = 128;
        hdelta = 64;
        dstoff = 2048 + (w - 4) * 512;
    }

    v4f acc0 = {0.f, 0.f, 0.f, 0.f};   // O partial, dims 0..15
    v4f acc1 = {0.f, 0.f, 0.f, 0.f};   // O partial, dims 16..31
    v4f dden = {0.f, 0.f, 0.f, 0.f};   // den (all 16 cols equal)

    // Prologue: stage first chunk (both halves) into buffer 0.
    gload_lds16(gsrc,          &tiles[0][dstoff]);
    gload_lds16(gsrc + hdelta, &tiles[0][4096 + dstoff]);
    gsrc += gdelta;
    __syncthreads();

    for (int c = c0; c < c1; ++c) {
        const int cc = c - c0;
        const bf16_t* tb = tiles[cc & 1];

        // Issue next chunk's staging loads first; they stay in flight across
        // this chunk's compute and are drained by the end-of-chunk barrier.
        if (c + 1 < c1) {
            bf16_t* nt = tiles[(cc + 1) & 1];
            gload_lds16(gsrc,          &nt[dstoff]);
            gload_lds16(gsrc + hdelta, &nt[4096 + dstoff]);
            gsrc += gdelta;
        }

#pragma unroll
        for (int h = 0; h < 2; ++h) {
            const bf16_t* th = tb + h * 4096;

            // --- GEMM1: S subtile t, column n=l16 <-> key kc+h*64+4*n+t ---
            v4f s[4];
#pragma unroll
            for (int t = 0; t < 4; ++t) {
                v8bf b = *(const v8bf*)&th[t * 512 + lane * 8];
                s[t] = __builtin_amdgcn_mfma_f32_16x16x32_bf16(afrag, b,
                            (v4f){0.f, 0.f, 0.f, 0.f}, 0, 0, 0);
            }

            // --- exp2 + pack 4 bf16 -> one b64 store per r ---
            // C-layout: (q=quad*4+r, col l16) = S[q][key kc+h*64+4*l16+t];
            // store at P position 4*l16+t (slab reused across halves).
#pragma unroll
            for (int r = 0; r < 4; ++r) {
                union { bf16_t hv[4]; unsigned long long u; } pk;
#pragma unroll
                for (int t = 0; t < 4; ++t)
                    pk.hv[t] = (bf16_t)__builtin_amdgcn_exp2f(s[t][r]);
                *(unsigned long long*)&p_lds[(quad * 4 + r) * PSTRIDE + 4 * l16] = pk.u;
            }

            // --- GEMM2: O[q][d] += P[q][k] V[k][d]; den rides the MFMA pipe
            // via an all-ones B-frag (wave-local LDS, in-order reads). ---
            v8bf a20 = *(const v8bf*)&p_lds[l16 * PSTRIDE + quad * 8];      // pos 0..31
            v8bf a21 = *(const v8bf*)&p_lds[l16 * PSTRIDE + 32 + quad * 8]; // pos 32..63
            v8bf b00 = *(const v8bf*)&th[2048 + 0 * 512 + lane * 8];  // hh0,g0
            v8bf b01 = *(const v8bf*)&th[2048 + 1 * 512 + lane * 8];  // hh0,g1
            v8bf b10 = *(const v8bf*)&th[2048 + 2 * 512 + lane * 8];  // hh1,g0
            v8bf b11 = *(const v8bf*)&th[2048 + 3 * 512 + lane * 8];  // hh1,g1
            acc0 = __builtin_amdgcn_mfma_f32_16x16x32_bf16(a20, b00, acc0, 0, 0, 0);
            acc1 = __builtin_amdgcn_mfma_f32_16x16x32_bf16(a20, b10, acc1, 0, 0, 0);
            dden = __builtin_amdgcn_mfma_f32_16x16x32_bf16(a20, ones, dden, 0, 0, 0);
            acc0 = __builtin_amdgcn_mfma_f32_16x16x32_bf16(a21, b01, acc0, 0, 0, 0);
            acc1 = __builtin_amdgcn_mfma_f32_16x16x32_bf16(a21, b11, acc1, 0, 0, 0);
            dden = __builtin_amdgcn_mfma_f32_16x16x32_bf16(a21, ones, dden, 0, 0, 0);
        }

        __syncthreads();
    }

    // --- epilogue: each wave owns its 16 queries outright; den comes straight
    // out of the MFMA accumulator (all 16 cols equal). ---
    float* pn = part_num + (size_t)ks * NPT * DIM;
#pragma unroll
    for (int r = 0; r < 4; ++r) {
        int gq = q0w + quad * 4 + r;
        pn[(size_t)gq * DIM + l16]      = acc0[r];
        pn[(size_t)gq * DIM + 16 + l16] = acc1[r];
    }
    if (l16 == 0) {
#pragma unroll
        for (int r = 0; r < 4; ++r)
            part_den[ks * NPT + q0w + quad * 4 + r] = dden[r];
    }
}

// Reduce KSEG partials, apply eta-step, write Xnext + next iteration's bf16
// rows/cols. Tiled 32q x 32d with LDS transpose so every global access is
// coalesced; pass 1 reads partials as float4 (latency-bound at ~1.1
// blocks/CU -> MLP matters). Grid = NPT/32 = 288 blocks x 256 threads.
__global__ __launch_bounds__(256, 4)
void reduce_kernel(const float* __restrict__ part_num,
                   const float* __restrict__ part_den,
                   const float* __restrict__ Xcur,
                   float* __restrict__ Xnext,
                   bf16_t* __restrict__ rows_out,
                   bf16_t* __restrict__ cols_out) {
    __shared__ float tnum[32][33];
    __shared__ float txn[32][33];
    __shared__ float tden[32];

    const int tid = threadIdx.x;
    const int q0  = blockIdx.x * 32;

    // pass 1 (q-major, coalesced float4 partial reads: 256 thr = 32q x 8dq)
    {
        int qq = tid >> 3, dq = tid & 7;
        v4f s = {0.f, 0.f, 0.f, 0.f};
#pragma unroll
        for (int ss = 0; ss < KSEG; ++ss)
            s += *(const v4f*)&part_num[((size_t)ss * NPT + q0 + qq) * DIM + dq * 4];
#pragma unroll
        for (int k = 0; k < 4; ++k) tnum[qq][dq * 4 + k] = s[k];
    }
    if (tid < 32) {
        float s = 0.f;
#pragma unroll
        for (int ss = 0; ss < KSEG; ++ss)
            s += part_den[ss * NPT + q0 + tid];
        tden[tid] = s;
    }
    __syncthreads();

    // pass 2 (d-major: Xcur read, Xnext + cols_out writes coalesced)
#pragma unroll
    for (int j = 0; j < 4; ++j) {
        int idx = tid + j * 256;
        int d = idx >> 5, qq = idx & 31;
        float num = tnum[qq][d];
        float dn  = tden[qq];
        float xo  = Xcur[d * NPT + q0 + qq];
        float xn  = ETA * num / dn + (1.0f - ETA) * xo;
        Xnext[d * NPT + q0 + qq] = xn;
        cols_out[(size_t)d * NPT + q0 + qq] = (bf16_t)xn;
        txn[qq][d] = xn;
    }
    __syncthreads();

    // pass 3 (q-major: rows_out coalesced)
#pragma unroll
    for (int j = 0; j < 4; ++j) {
        int idx = tid + j * 256;
        int qq = idx >> 5, d = idx & 31;
        rows_out[(size_t)(q0 + qq) * DIM + d] = (bf16_t)txn[qq][d];
    }
}

extern "C" void kernel_launch(void* const* d_in, const int* in_sizes, int n_in,
                              void* d_out, int out_size, void* d_ws, size_t ws_size,
                              hipStream_t stream) {
    const float* x_in = (const float*)d_in[0];
    float* out = (float*)d_out;

    const size_t DN = (size_t)DIM * NPT;
    // Workspace: 4 bf16 pack buffers (ping-pong), fp32 partials.
    bf16_t* rows0 = (bf16_t*)d_ws;
    bf16_t* cols0 = rows0 + DN;
    bf16_t* rows1 = cols0 + DN;
    bf16_t* cols1 = rows1 + DN;
    float* part_num = (float*)(cols1 + DN);                 // KSEG * NPT * DIM f32
    float* part_den = part_num + (size_t)KSEG * NPT * DIM;  // KSEG * NPT f32

    const int pack_blocks = (DIM * NPT + 255) / 256;   // 1152
    pack_kernel<<<pack_blocks, 256, 0, stream>>>(x_in, rows0, cols0, out);

    for (int it = 0; it < NITER; ++it) {
        const float* Xcur = (it == 0) ? x_in : out + (size_t)it * DN;
        bf16_t* rin  = (it & 1) ? rows1 : rows0;
        bf16_t* cin  = (it & 1) ? cols1 : cols0;
        bf16_t* rout = (it & 1) ? rows0 : rows1;
        bf16_t* cout = (it & 1) ? cols0 : cols1;
        msattn_kernel<<<dim3(NQB, KSEG), 512, 0, stream>>>(Xcur, rin, cin,
                                                           part_num, part_den);
        reduce_kernel<<<NPT / 32, 256, 0, stream>>>(part_num, part_den, Xcur,
                                                    out + (size_t)(it + 1) * DN,
                                                    rout, cout);
    }
}